// Round 5
// baseline (343.398 us; speedup 1.0000x reference)
//
#include <hip/hip_runtime.h>

// B=16, N=512, T=64, D=64, H=8, K=3, DK=8
// grid = 8192 blocks (one per (b,n)), 256 threads (4 waves), 3 blocks/CU
// All matmuls on MFMA 16x16x32 bf16. R5: operand-swapped (transposed) MFMAs so
// p/out stores are float4 and conv LDS writes are b64; in-lane softmax rows.

#define OUT_ELEMS 33554432ull   // B*N*T*D

typedef unsigned short u16;
typedef unsigned int u32;
typedef unsigned long long u64;
typedef __attribute__((ext_vector_type(8))) short short8;
typedef __attribute__((ext_vector_type(4))) float f32x4;

__device__ __forceinline__ u16 f2b(float f) {  // f32 -> bf16 RNE
  u32 u = __float_as_uint(f);
  return (u16)((u + 0x7fffu + ((u >> 16) & 1u)) >> 16);
}

// ws (ushort) layout, MFMA fragment order (lane l = (idx>>3)&63, elem e = idx&7):
//  wsq [0,12288):     frag f=(j*2+kk)*4+nt : Wq[d=nt*16+(l&15)][c=kk*32+(l>>4)*8+e][j]
//  wsk [12288,24576): same for Wk
//  wsv [24576,28672): frag f=w*2+kk (A-op): Wv[d=16w+(l&15)][c=kk*32+(l>>4)*8+e]
//  wso [28672,32768): frag f=kk*4+nt : Wo[dp=nt*16+(l&15)][c=kk*32+(l>>4)*8+e]
__global__ __launch_bounds__(256) void prep_weights(
    const float* __restrict__ Wq, const float* __restrict__ Wk,
    const float* __restrict__ Wv, const float* __restrict__ Wo,
    u16* __restrict__ ws) {
  int i = blockIdx.x * 256 + threadIdx.x;  // 0..32767
  int lane = (i >> 3) & 63;
  int e = i & 7;
  int m15 = lane & 15, g = lane >> 4;
  if (i < 12288) {
    int f = i >> 9;  // 0..23
    int j = f >> 3, kk = (f >> 2) & 1, nt = f & 3;
    int d = nt * 16 + m15, c = kk * 32 + g * 8 + e;
    ws[i] = f2b(Wq[(d * 64 + c) * 3 + j]);
  } else if (i < 24576) {
    int f = (i - 12288) >> 9;
    int j = f >> 3, kk = (f >> 2) & 1, nt = f & 3;
    int d = nt * 16 + m15, c = kk * 32 + g * 8 + e;
    ws[i] = f2b(Wk[(d * 64 + c) * 3 + j]);
  } else if (i < 28672) {
    int f = (i - 24576) >> 9;  // 0..7
    int w = f >> 1, kk = f & 1;
    int d = 16 * w + m15, c = kk * 32 + g * 8 + e;
    ws[i] = f2b(Wv[d * 64 + c]);
  } else if (i < 32768) {
    int f = (i - 28672) >> 9;  // 0..7
    int kk = f >> 2, nt = f & 3;
    int dp = nt * 16 + m15, c = kk * 32 + g * 8 + e;
    ws[i] = f2b(Wo[dp * 64 + c]);
  }
}

__global__ __launch_bounds__(256, 3) void fused_attn(
    const float* __restrict__ q_in, const float* __restrict__ k_in,
    const float* __restrict__ v_in, const int* __restrict__ mask,
    const u16* __restrict__ ws,
    const float* __restrict__ bq, const float* __restrict__ bk,
    const float* __restrict__ bv, const float* __restrict__ bo,
    float* __restrict__ out, float* __restrict__ p_out) {
  // LDS tiles: row pitch 72 bf16 (144B). xb rows 0,1 = zero pad.
  __shared__ __align__(16) u16 xb[66 * 72];  // staging; rows 0..63 alias pb later
  __shared__ __align__(16) u16 qb[64 * 72];  // q (scaled) [t][d]
  __shared__ __align__(16) u16 kb[64 * 72];  // k [s][d]
  __shared__ __align__(16) u16 vT[64 * 72];  // v^T [d][s]
  __shared__ __align__(16) u16 xo[64 * 72];  // attn out x [t][d]
  __shared__ __align__(16) u16 mskw[256];    // mask bits [row t][4 x u16]

  const int tid = threadIdx.x;
  const int bid = blockIdx.x;   // b*512 + n
  const int b = bid >> 9;
  const int l = tid & 63;
  const int w = tid >> 6;       // wave 0..3
  const int g = l >> 4;         // lane group 0..3
  const int m15 = l & 15;

  const u16* wsq = ws;
  const u16* wsk = ws + 12288;
  const u16* wsv = ws + 24576;
  const u16* wso = ws + 28672;

  const short8 z8 = {0, 0, 0, 0, 0, 0, 0, 0};
  const int rowt = 16 * w + m15;      // this lane's t (QK/out) / row index

  // zero xb pad rows 0,1: 144 u16 = 72 dwords
  if (tid < 72) ((u32*)xb)[tid] = 0u;

  auto stage = [&](const float* __restrict__ src) {
#pragma unroll
    for (int cc = 0; cc < 2; cc++) {
      int c = tid * 2 + cc;              // 0..511 chunks of 8 floats
      const float* p = src + c * 8;
      float4 x0 = *(const float4*)(p);
      float4 x1 = *(const float4*)(p + 4);
      u32 p0 = (u32)f2b(x0.x) | ((u32)f2b(x0.y) << 16);
      u32 p1 = (u32)f2b(x0.z) | ((u32)f2b(x0.w) << 16);
      u32 p2 = (u32)f2b(x1.x) | ((u32)f2b(x1.y) << 16);
      u32 p3 = (u32)f2b(x1.z) | ((u32)f2b(x1.w) << 16);
      int r = c >> 3, k8 = (c & 7) * 8;
      *(uint4*)(xb + (r + 2) * 72 + k8) = make_uint4(p0, p1, p2, p3);
    }
  };

  // conv, transposed D[d][t]: acc[sb] covers d = sb*16+g*4+r, t = rowt.
  auto conv = [&](const u16* __restrict__ wpack, const float* __restrict__ bias,
                  float scale, u16* __restrict__ dst) {
    f32x4 acc[4];
#pragma unroll
    for (int sb = 0; sb < 4; sb++) {
      float4 bb = *(const float4*)(bias + sb * 16 + g * 4);
      acc[sb] = (f32x4){bb.x, bb.y, bb.z, bb.w};
    }
#pragma unroll
    for (int j = 0; j < 3; j++) {
#pragma unroll
      for (int kk = 0; kk < 2; kk++) {
        short8 xf = *(const short8*)(xb + (rowt + j) * 72 + kk * 32 + g * 8);
#pragma unroll
        for (int sb = 0; sb < 4; sb++) {
          short8 wf = *(const short8*)(wpack + (size_t)((j * 2 + kk) * 4 + sb) * 512 + l * 8);
          acc[sb] = __builtin_amdgcn_mfma_f32_16x16x32_bf16(wf, xf, acc[sb], 0, 0, 0);
        }
      }
    }
#pragma unroll
    for (int sb = 0; sb < 4; sb++) {
      u32 lo = (u32)f2b(acc[sb][0] * scale) | ((u32)f2b(acc[sb][1] * scale) << 16);
      u32 hi = (u32)f2b(acc[sb][2] * scale) | ((u32)f2b(acc[sb][3] * scale) << 16);
      *(uint2*)(dst + rowt * 72 + sb * 16 + g * 4) = make_uint2(lo, hi);
    }
  };

  // ---------- q ----------
  stage(q_in + (size_t)bid * 4096);
  __syncthreads();
  conv(wsq, bq, 0.35355339059327373f, qb);
  __syncthreads();
  // ---------- k ----------
  stage(k_in + (size_t)bid * 4096);
  __syncthreads();
  conv(wsk, bk, 1.0f, kb);
  __syncthreads();
  // ---------- v ----------
  stage(v_in + (size_t)bid * 4096);
  __syncthreads();
  {  // v-proj -> vT[d][s] (same orientation as R4)
    f32x4 acc[4];
    float bm0 = bv[16 * w + g * 4 + 0], bm1 = bv[16 * w + g * 4 + 1];
    float bm2 = bv[16 * w + g * 4 + 2], bm3 = bv[16 * w + g * 4 + 3];
#pragma unroll
    for (int nt = 0; nt < 4; nt++) acc[nt] = (f32x4){bm0, bm1, bm2, bm3};
#pragma unroll
    for (int kk = 0; kk < 2; kk++) {
      short8 a = *(const short8*)(wsv + (size_t)(w * 2 + kk) * 512 + l * 8);
#pragma unroll
      for (int nt = 0; nt < 4; nt++) {
        short8 bf = *(const short8*)(xb + (nt * 16 + m15 + 2) * 72 + kk * 32 + g * 8);
        acc[nt] = __builtin_amdgcn_mfma_f32_16x16x32_bf16(a, bf, acc[nt], 0, 0, 0);
      }
    }
#pragma unroll
    for (int nt = 0; nt < 4; nt++)
#pragma unroll
      for (int r = 0; r < 4; r++)
        vT[(16 * w + g * 4 + r) * 72 + nt * 16 + m15] = f2b(acc[nt][r]);
  }

  // ---------- pack mask bits: mskw[row*4+qt] = bits of mask[b][row][qt*16..+15] ----------
  {
    int row = tid >> 2, qt = tid & 3;
    const int* mp = mask + (size_t)b * 4096 + row * 64 + qt * 16;
    u32 bits = 0;
#pragma unroll
    for (int i4 = 0; i4 < 4; i4++) {
      int4 mv = *(const int4*)(mp + i4 * 4);
      bits |= ((u32)mv.x << (i4 * 4)) | ((u32)mv.y << (i4 * 4 + 1)) |
              ((u32)mv.z << (i4 * 4 + 2)) | ((u32)mv.w << (i4 * 4 + 3));
    }
    mskw[row * 4 + qt] = (u16)bits;
  }
  __syncthreads();  // vT + mskw complete; xb free -> pb

  u16* pb = xb;  // P staging [t][s] bf16, rows 0..63; wave-private rows
  const u64 mg = ((const u64*)mskw)[rowt] >> (g * 4);  // bit (sb*16+r) = mask[rowt][sb*16+g*4+r]
  const int t64 = rowt * 64;

  // ---------- head loop: zero barriers ----------
#pragma unroll 1
  for (int h = 0; h < 8; h++) {
    // QK^T transposed: D[s][t], lane: t=rowt, s=sb*16+g*4+r. K=8 padded to 32.
    short8 bq8 = *(const short8*)(qb + rowt * 72 + h * 8);
    if (g != 0) bq8 = z8;
    f32x4 s4[4];
#pragma unroll
    for (int sb = 0; sb < 4; sb++) {
      short8 ak = *(const short8*)(kb + (sb * 16 + m15) * 72 + h * 8);
      if (g != 0) ak = z8;
      f32x4 zero = {0.f, 0.f, 0.f, 0.f};
      s4[sb] = __builtin_amdgcn_mfma_f32_16x16x32_bf16(ak, bq8, zero, 0, 0, 0);
    }
    // softmax along s: all 16 values in-lane (+ reduce over 4 lane-groups)
    float e[4][4];
    float rs = 0.f;
#pragma unroll
    for (int sb = 0; sb < 4; sb++)
#pragma unroll
      for (int r = 0; r < 4; r++) {
        float v = ((mg >> (sb * 16 + r)) & 1ull) ? __expf(s4[sb][r]) : 0.f;
        e[sb][r] = v;
        rs += v;
      }
    rs += __shfl_xor(rs, 16);
    rs += __shfl_xor(rs, 32);
    float ri = __fdividef(1.f, rs + 1e-30f);
    float* pg = p_out + ((size_t)bid * 8 + h) * 4096 + t64;
#pragma unroll
    for (int sb = 0; sb < 4; sb++) {
      float4 pv = make_float4(e[sb][0] * ri, e[sb][1] * ri, e[sb][2] * ri, e[sb][3] * ri);
      *(float4*)(pg + sb * 16 + g * 4) = pv;
      u32 lo = (u32)f2b(pv.x) | ((u32)f2b(pv.y) << 16);
      u32 hi = (u32)f2b(pv.z) | ((u32)f2b(pv.w) << 16);
      *(uint2*)(pb + rowt * 72 + sb * 16 + g * 4) = make_uint2(lo, hi);
    }
    // PV: D[t][dk], A = P rows (t-block w), B = vT rows dk (cols 8..15 dup/discard)
    f32x4 xacc = {0.f, 0.f, 0.f, 0.f};
#pragma unroll
    for (int kk = 0; kk < 2; kk++) {
      short8 ap = *(const short8*)(pb + rowt * 72 + kk * 32 + g * 8);
      short8 bv8 = *(const short8*)(vT + (h * 8 + (m15 & 7)) * 72 + kk * 32 + g * 8);
      xacc = __builtin_amdgcn_mfma_f32_16x16x32_bf16(ap, bv8, xacc, 0, 0, 0);
    }
    if (m15 < 8) {
#pragma unroll
      for (int r = 0; r < 4; r++)
        xo[(16 * w + g * 4 + r) * 72 + h * 8 + m15] = f2b(xacc[r]);
    }
  }

  // ---------- output projection, transposed: D[dp][t], float4 stores ----------
  {
    f32x4 acc[4];
#pragma unroll
    for (int sb = 0; sb < 4; sb++) {
      float4 bb = *(const float4*)(bo + sb * 16 + g * 4);
      acc[sb] = (f32x4){bb.x, bb.y, bb.z, bb.w};
    }
#pragma unroll
    for (int kk = 0; kk < 2; kk++) {
      short8 xf = *(const short8*)(xo + rowt * 72 + kk * 32 + g * 8);
#pragma unroll
      for (int sb = 0; sb < 4; sb++) {
        short8 wf = *(const short8*)(wso + (size_t)(kk * 4 + sb) * 512 + l * 8);
        acc[sb] = __builtin_amdgcn_mfma_f32_16x16x32_bf16(wf, xf, acc[sb], 0, 0, 0);
      }
    }
    float* ob = out + (size_t)bid * 4096 + t64;
#pragma unroll
    for (int sb = 0; sb < 4; sb++)
      *(float4*)(ob + sb * 16 + g * 4) = make_float4(acc[sb][0], acc[sb][1], acc[sb][2], acc[sb][3]);
  }
}

extern "C" void kernel_launch(void* const* d_in, const int* in_sizes, int n_in,
                              void* d_out, int out_size, void* d_ws, size_t ws_size,
                              hipStream_t stream) {
  const float* query = (const float*)d_in[0];
  const float* key   = (const float*)d_in[1];
  const float* value = (const float*)d_in[2];
  const int*   mask  = (const int*)d_in[4];
  const float* Wq = (const float*)d_in[5];
  const float* bq = (const float*)d_in[6];
  const float* Wk = (const float*)d_in[7];
  const float* bk = (const float*)d_in[8];
  const float* Wv = (const float*)d_in[9];
  const float* bv = (const float*)d_in[10];
  const float* Wo = (const float*)d_in[11];
  const float* bo = (const float*)d_in[12];

  float* out = (float*)d_out;
  float* p_out = out + OUT_ELEMS;
  u16* ws = (u16*)d_ws;

  hipLaunchKernelGGL(prep_weights, dim3(128), dim3(256), 0, stream,
                     Wq, Wk, Wv, Wo, ws);
  hipLaunchKernelGGL(fused_attn, dim3(8192), dim3(256), 0, stream,
                     query, key, value, mask, ws, bq, bk, bv, bo, out, p_out);
}

// Round 6
// 328.289 us; speedup vs baseline: 1.0460x; 1.0460x over previous
//
#include <hip/hip_runtime.h>

// B=16, N=512, T=64, D=64, H=8, K=3, DK=8
// grid = 8192 blocks (one per (b,n)), 256 threads (4 waves), 4 blocks/CU
// R6 = R4 kernel + xo aliased into dead qb slices (LDS 46.9->37.7 KB, 3->4 blocks/CU)

#define OUT_ELEMS 33554432ull   // B*N*T*D

typedef unsigned short u16;
typedef unsigned int u32;
typedef __attribute__((ext_vector_type(8))) short short8;
typedef __attribute__((ext_vector_type(4))) float f32x4;

__device__ __forceinline__ u16 f2b(float f) {  // f32 -> bf16 RNE
  u32 u = __float_as_uint(f);
  return (u16)((u + 0x7fffu + ((u >> 16) & 1u)) >> 16);
}

// ws (ushort) layout, MFMA fragment order (lane l = (idx>>3)&63, elem e = idx&7):
//  wsq [0,12288):     frag f=(j*2+kk)*4+nt : Wq[d=nt*16+(l&15)][c=kk*32+(l>>4)*8+e][j]
//  wsk [12288,24576): same for Wk
//  wsv [24576,28672): frag f=w*2+kk (A-op): Wv[d=16w+(l&15)][c=kk*32+(l>>4)*8+e]
//  wso [28672,32768): frag f=kk*4+nt (B-op): Wo[dp=nt*16+(l&15)][c=kk*32+(l>>4)*8+e]
__global__ __launch_bounds__(256) void prep_weights(
    const float* __restrict__ Wq, const float* __restrict__ Wk,
    const float* __restrict__ Wv, const float* __restrict__ Wo,
    u16* __restrict__ ws) {
  int i = blockIdx.x * 256 + threadIdx.x;  // 0..32767
  int lane = (i >> 3) & 63;
  int e = i & 7;
  int m15 = lane & 15, g = lane >> 4;
  if (i < 12288) {
    int f = i >> 9;  // 0..23
    int j = f >> 3, kk = (f >> 2) & 1, nt = f & 3;
    int d = nt * 16 + m15, c = kk * 32 + g * 8 + e;
    ws[i] = f2b(Wq[(d * 64 + c) * 3 + j]);
  } else if (i < 24576) {
    int f = (i - 12288) >> 9;
    int j = f >> 3, kk = (f >> 2) & 1, nt = f & 3;
    int d = nt * 16 + m15, c = kk * 32 + g * 8 + e;
    ws[i] = f2b(Wk[(d * 64 + c) * 3 + j]);
  } else if (i < 28672) {
    int f = (i - 24576) >> 9;  // 0..7
    int w = f >> 1, kk = f & 1;
    int d = 16 * w + m15, c = kk * 32 + g * 8 + e;
    ws[i] = f2b(Wv[d * 64 + c]);
  } else if (i < 32768) {
    int f = (i - 28672) >> 9;  // 0..7
    int kk = f >> 2, nt = f & 3;
    int dp = nt * 16 + m15, c = kk * 32 + g * 8 + e;
    ws[i] = f2b(Wo[dp * 64 + c]);
  }
}

__global__ __launch_bounds__(256, 4) void fused_attn(
    const float* __restrict__ q_in, const float* __restrict__ k_in,
    const float* __restrict__ v_in, const int* __restrict__ mask,
    const u16* __restrict__ ws,
    const float* __restrict__ bq, const float* __restrict__ bk,
    const float* __restrict__ bv, const float* __restrict__ bo,
    float* __restrict__ out, float* __restrict__ p_out) {
  // LDS tiles: row pitch 72 bf16 (144B, 16B-aligned). xb rows 0,1 = zero pad.
  __shared__ __align__(16) u16 xb[66 * 72];  // staging; rows 0..63 alias pb later
  __shared__ __align__(16) u16 qb[64 * 72];  // q (scaled) [t][d]; slice h -> x after PV-h
  __shared__ __align__(16) u16 kb[64 * 72];  // k [s][d]
  __shared__ __align__(16) u16 vT[64 * 72];  // v^T [d][s]

  const int tid = threadIdx.x;
  const int bid = blockIdx.x;   // b*512 + n
  const int b = bid >> 9;
  const int l = tid & 63;
  const int w = tid >> 6;       // wave 0..3
  const int g = l >> 4;         // lane group 0..3
  const int m15 = l & 15;

  const u16* wsq = ws;
  const u16* wsk = ws + 12288;
  const u16* wsv = ws + 24576;
  const u16* wso = ws + 28672;

  const short8 z8 = {0, 0, 0, 0, 0, 0, 0, 0};

  // zero xb pad rows 0,1: 2 rows * 72 u16 = 144 u16 = 72 dwords
  if (tid < 72) ((u32*)xb)[tid] = 0u;

  // ---------- helpers as lambdas ----------
  auto stage = [&](const float* __restrict__ src) {
#pragma unroll
    for (int cc = 0; cc < 2; cc++) {
      int c = tid * 2 + cc;              // 0..511 chunks of 8 floats
      const float* p = src + c * 8;
      float4 x0 = *(const float4*)(p);
      float4 x1 = *(const float4*)(p + 4);
      u32 p0 = (u32)f2b(x0.x) | ((u32)f2b(x0.y) << 16);
      u32 p1 = (u32)f2b(x0.z) | ((u32)f2b(x0.w) << 16);
      u32 p2 = (u32)f2b(x1.x) | ((u32)f2b(x1.y) << 16);
      u32 p3 = (u32)f2b(x1.z) | ((u32)f2b(x1.w) << 16);
      int r = c >> 3, k8 = (c & 7) * 8;
      *(uint4*)(xb + (r + 2) * 72 + k8) = make_uint4(p0, p1, p2, p3);
    }
  };

  auto conv = [&](const u16* __restrict__ wpack, const float* __restrict__ bias,
                  float scale, u16* __restrict__ dst) {
    f32x4 acc[4];
#pragma unroll
    for (int nt = 0; nt < 4; nt++) {
      float bb = bias[nt * 16 + m15];
      acc[nt] = (f32x4){bb, bb, bb, bb};
    }
#pragma unroll
    for (int j = 0; j < 3; j++) {
#pragma unroll
      for (int kk = 0; kk < 2; kk++) {
        short8 a = *(const short8*)(xb + (16 * w + m15 + j) * 72 + kk * 32 + g * 8);
#pragma unroll
        for (int nt = 0; nt < 4; nt++) {
          short8 bf = *(const short8*)(wpack + (size_t)((j * 2 + kk) * 4 + nt) * 512 + l * 8);
          acc[nt] = __builtin_amdgcn_mfma_f32_16x16x32_bf16(a, bf, acc[nt], 0, 0, 0);
        }
      }
    }
#pragma unroll
    for (int nt = 0; nt < 4; nt++)
#pragma unroll
      for (int r = 0; r < 4; r++)
        dst[(16 * w + g * 4 + r) * 72 + nt * 16 + m15] = f2b(acc[nt][r] * scale);
  };

  // ---------- stage q, conv q -> qb (scale folded) ----------
  stage(q_in + (size_t)bid * 4096);
  __syncthreads();
  conv(wsq, bq, 0.35355339059327373f, qb);
  __syncthreads();

  // ---------- stage k, conv k -> kb ----------
  stage(k_in + (size_t)bid * 4096);
  __syncthreads();
  conv(wsk, bk, 1.0f, kb);
  __syncthreads();

  // ---------- stage v, v-proj -> vT[d][s] ----------
  stage(v_in + (size_t)bid * 4096);
  __syncthreads();
  {
    f32x4 acc[4];
    float bm0 = bv[16 * w + g * 4 + 0], bm1 = bv[16 * w + g * 4 + 1];
    float bm2 = bv[16 * w + g * 4 + 2], bm3 = bv[16 * w + g * 4 + 3];
#pragma unroll
    for (int nt = 0; nt < 4; nt++) acc[nt] = (f32x4){bm0, bm1, bm2, bm3};
#pragma unroll
    for (int kk = 0; kk < 2; kk++) {
      short8 a = *(const short8*)(wsv + (size_t)(w * 2 + kk) * 512 + l * 8);
#pragma unroll
      for (int nt = 0; nt < 4; nt++) {
        short8 bf = *(const short8*)(xb + (nt * 16 + m15 + 2) * 72 + kk * 32 + g * 8);
        acc[nt] = __builtin_amdgcn_mfma_f32_16x16x32_bf16(a, bf, acc[nt], 0, 0, 0);
      }
    }
#pragma unroll
    for (int nt = 0; nt < 4; nt++)
#pragma unroll
      for (int r = 0; r < 4; r++)
        vT[(16 * w + g * 4 + r) * 72 + nt * 16 + m15] = f2b(acc[nt][r]);
  }

  // mask bits: bit nt*4+r = mask[b][t=16w+g*4+r][s=nt*16+m15]
  u32 mb = 0;
#pragma unroll
  for (int nt = 0; nt < 4; nt++)
#pragma unroll
    for (int r = 0; r < 4; r++)
      if (mask[(size_t)b * 4096 + (16 * w + g * 4 + r) * 64 + nt * 16 + m15])
        mb |= 1u << (nt * 4 + r);
  __syncthreads();  // vT complete (cross-wave); xb free -> pb

  u16* pb = xb;  // P staging [t][s], rows 0..63; intra-wave use only

  // ---------- head loop: ZERO barriers (qb/pb rows are wave-private; vT,kb read-only) ----------
#pragma unroll 1
  for (int h = 0; h < 8; h++) {
    // QK^T: K=8 padded to 32 (only lane-group 0 carries data)
    short8 aq = *(const short8*)(qb + (16 * w + m15) * 72 + h * 8);
    if (g != 0) aq = z8;
    f32x4 s4[4];
#pragma unroll
    for (int nt = 0; nt < 4; nt++) {
      short8 bk8 = *(const short8*)(kb + (nt * 16 + m15) * 72 + h * 8);
      if (g != 0) bk8 = z8;
      f32x4 zero = {0.f, 0.f, 0.f, 0.f};
      s4[nt] = __builtin_amdgcn_mfma_f32_16x16x32_bf16(aq, bk8, zero, 0, 0, 0);
    }
    // masked softmax over s (row = t fixed per (g,r); cols across 16 lanes x 4 nt)
    float e[4][4];
    float rs0 = 0.f, rs1 = 0.f, rs2 = 0.f, rs3 = 0.f;
#pragma unroll
    for (int nt = 0; nt < 4; nt++) {
      e[nt][0] = (mb & (1u << (nt * 4 + 0))) ? __expf(s4[nt][0]) : 0.f;
      e[nt][1] = (mb & (1u << (nt * 4 + 1))) ? __expf(s4[nt][1]) : 0.f;
      e[nt][2] = (mb & (1u << (nt * 4 + 2))) ? __expf(s4[nt][2]) : 0.f;
      e[nt][3] = (mb & (1u << (nt * 4 + 3))) ? __expf(s4[nt][3]) : 0.f;
      rs0 += e[nt][0]; rs1 += e[nt][1]; rs2 += e[nt][2]; rs3 += e[nt][3];
    }
#pragma unroll
    for (int off = 1; off <= 8; off <<= 1) {
      rs0 += __shfl_xor(rs0, off);
      rs1 += __shfl_xor(rs1, off);
      rs2 += __shfl_xor(rs2, off);
      rs3 += __shfl_xor(rs3, off);
    }
    float ri0 = __fdividef(1.f, rs0 + 1e-30f);
    float ri1 = __fdividef(1.f, rs1 + 1e-30f);
    float ri2 = __fdividef(1.f, rs2 + 1e-30f);
    float ri3 = __fdividef(1.f, rs3 + 1e-30f);
    float* pg = p_out + (((size_t)bid * 8 + h) * 4096);
#pragma unroll
    for (int nt = 0; nt < 4; nt++) {
      float p0 = e[nt][0] * ri0, p1 = e[nt][1] * ri1;
      float p2 = e[nt][2] * ri2, p3 = e[nt][3] * ri3;
      pg[(16 * w + g * 4 + 0) * 64 + nt * 16 + m15] = p0;
      pg[(16 * w + g * 4 + 1) * 64 + nt * 16 + m15] = p1;
      pg[(16 * w + g * 4 + 2) * 64 + nt * 16 + m15] = p2;
      pg[(16 * w + g * 4 + 3) * 64 + nt * 16 + m15] = p3;
      pb[(16 * w + g * 4 + 0) * 72 + nt * 16 + m15] = f2b(p0);
      pb[(16 * w + g * 4 + 1) * 72 + nt * 16 + m15] = f2b(p1);
      pb[(16 * w + g * 4 + 2) * 72 + nt * 16 + m15] = f2b(p2);
      pb[(16 * w + g * 4 + 3) * 72 + nt * 16 + m15] = f2b(p3);
    }
    // PV: x[t][h*8+dk] = sum_s P[t][s] v[s][h*8+dk]; N-cols 8..15 duplicated, discarded
    f32x4 xacc = {0.f, 0.f, 0.f, 0.f};
#pragma unroll
    for (int kk = 0; kk < 2; kk++) {
      short8 ap = *(const short8*)(pb + (16 * w + m15) * 72 + kk * 32 + g * 8);
      short8 bv8 = *(const short8*)(vT + (h * 8 + (m15 & 7)) * 72 + kk * 32 + g * 8);
      xacc = __builtin_amdgcn_mfma_f32_16x16x32_bf16(ap, bv8, xacc, 0, 0, 0);
    }
    // store x into the dead q slice of head h (wave-private rows; after QK-h read)
    if (m15 < 8) {
#pragma unroll
      for (int r = 0; r < 4; r++)
        qb[(16 * w + g * 4 + r) * 72 + h * 8 + m15] = f2b(xacc[r]);
    }
  }

  // ---------- output projection (qb now holds x; rows wave-private, no barrier) ----------
  {
    f32x4 acc[4];
#pragma unroll
    for (int nt = 0; nt < 4; nt++) {
      float bb = bo[nt * 16 + m15];
      acc[nt] = (f32x4){bb, bb, bb, bb};
    }
#pragma unroll
    for (int kk = 0; kk < 2; kk++) {
      short8 ax = *(const short8*)(qb + (16 * w + m15) * 72 + kk * 32 + g * 8);
#pragma unroll
      for (int nt = 0; nt < 4; nt++) {
        short8 bf = *(const short8*)(wso + (size_t)(kk * 4 + nt) * 512 + l * 8);
        acc[nt] = __builtin_amdgcn_mfma_f32_16x16x32_bf16(ax, bf, acc[nt], 0, 0, 0);
      }
    }
#pragma unroll
    for (int nt = 0; nt < 4; nt++)
#pragma unroll
      for (int r = 0; r < 4; r++)
        out[(size_t)bid * 4096 + (16 * w + g * 4 + r) * 64 + nt * 16 + m15] = acc[nt][r];
  }
}

extern "C" void kernel_launch(void* const* d_in, const int* in_sizes, int n_in,
                              void* d_out, int out_size, void* d_ws, size_t ws_size,
                              hipStream_t stream) {
  const float* query = (const float*)d_in[0];
  const float* key   = (const float*)d_in[1];
  const float* value = (const float*)d_in[2];
  const int*   mask  = (const int*)d_in[4];
  const float* Wq = (const float*)d_in[5];
  const float* bq = (const float*)d_in[6];
  const float* Wk = (const float*)d_in[7];
  const float* bk = (const float*)d_in[8];
  const float* Wv = (const float*)d_in[9];
  const float* bv = (const float*)d_in[10];
  const float* Wo = (const float*)d_in[11];
  const float* bo = (const float*)d_in[12];

  float* out = (float*)d_out;
  float* p_out = out + OUT_ELEMS;
  u16* ws = (u16*)d_ws;

  hipLaunchKernelGGL(prep_weights, dim3(128), dim3(256), 0, stream,
                     Wq, Wk, Wv, Wo, ws);
  hipLaunchKernelGGL(fused_attn, dim3(8192), dim3(256), 0, stream,
                     query, key, value, mask, ws, bq, bk, bv, bo, out, p_out);
}